// Round 1
// baseline (268.378 us; speedup 1.0000x reference)
//
#include <hip/hip_runtime.h>
#include <math.h>

// Problem constants
#define TM 16384   // B*C*T rows
#define NN 512     // DOUT
#define KDIM 1536  // DIN
#define BM 128
#define BN 128
#define BKS 32
#define APAD 40    // halves per LDS row (pad 32 -> 40 to break bank conflicts)

typedef _Float16 f16x8 __attribute__((ext_vector_type(8)));
typedef float f32x4 __attribute__((ext_vector_type(4)));

__device__ __forceinline__ unsigned short f16bits(_Float16 h) {
  union { _Float16 h; unsigned short u; } cv; cv.h = h; return cv.u;
}

// ---------------------------------------------------------------------------
// Kernel 1: W1 [K=1536][N=512] fp32 -> transposed fp16 hi/lo  W1t[n][k]
// lo scaled by 2^11 to stay in fp16 normal range.
// ---------------------------------------------------------------------------
__global__ __launch_bounds__(256) void convert_w1_kernel(
    const float* __restrict__ W1,
    unsigned short* __restrict__ W1th,
    unsigned short* __restrict__ W1tl)
{
  __shared__ unsigned short th[64][72];
  __shared__ unsigned short tl[64][72];
  const int k0 = blockIdx.x * 64;
  const int n0 = blockIdx.y * 64;
  const int tid = threadIdx.x;
#pragma unroll
  for (int i = 0; i < 16; ++i) {
    int idx = tid + i * 256;          // 0..4095
    int kk = idx >> 6, nn = idx & 63;
    float f = W1[(size_t)(k0 + kk) * NN + n0 + nn];
    _Float16 h = (_Float16)f;
    _Float16 l = (_Float16)((f - (float)h) * 2048.0f);
    th[nn][kk] = f16bits(h);
    tl[nn][kk] = f16bits(l);
  }
  __syncthreads();
#pragma unroll
  for (int i = 0; i < 16; ++i) {
    int idx = tid + i * 256;
    int nn = idx >> 6, kk = idx & 63;
    size_t o = (size_t)(n0 + nn) * KDIM + k0 + kk;
    W1th[o] = th[nn][kk];
    W1tl[o] = tl[nn][kk];
  }
}

// ---------------------------------------------------------------------------
// Kernel 2: GEMM z = q @ W1 + b via fp16 split-3 MFMA, fused epilogue
// partial[row] = sum_{cols in this N-tile} tanh(z)*Vw[col] -> raw_part[by][row]
// ---------------------------------------------------------------------------
__global__ __launch_bounds__(256) void gemm_score_kernel(
    const float* __restrict__ query,
    const unsigned short* __restrict__ W1th,
    const unsigned short* __restrict__ W1tl,
    const float* __restrict__ W1b,
    const float* __restrict__ Vw,
    float* __restrict__ raw_part)
{
  __shared__ _Float16 Ah[BM][APAD];
  __shared__ _Float16 Al[BM][APAD];
  __shared__ _Float16 Bh[BN][APAD];
  __shared__ _Float16 Bl[BN][APAD];
  __shared__ float red[2][BM];

  const int tid = threadIdx.x;
  const int lane = tid & 63;
  const int w = tid >> 6;
  const int wr = w >> 1, wc = w & 1;       // 2x2 waves, each 64x64
  const int lrow = lane & 15;
  const int lk = (lane >> 4) * 8;
  const int m0 = blockIdx.x * BM;
  const int n0 = blockIdx.y * BN;

  f32x4 zero = {0.f, 0.f, 0.f, 0.f};
  f32x4 acc[4][4];   // hh accumulation
  f32x4 acc2[4][4];  // (hl + lh) * 2^11 accumulation
#pragma unroll
  for (int m = 0; m < 4; ++m)
#pragma unroll
    for (int n = 0; n < 4; ++n) { acc[m][n] = zero; acc2[m][n] = zero; }

  for (int kt = 0; kt < KDIM / BKS; ++kt) {
    const int k0 = kt * BKS;
    __syncthreads();
    // ---- stage A: 128x32 fp32 -> hi/lo fp16 (lo scaled 2^11) ----
#pragma unroll
    for (int i = 0; i < 4; ++i) {
      int q = tid + i * 256;               // 0..1023 float4 chunks
      int row = q >> 3, jc = q & 7;
      const float4 v = *reinterpret_cast<const float4*>(
          &query[(size_t)(m0 + row) * KDIM + k0 + jc * 4]);
      _Float16 h0 = (_Float16)v.x, h1 = (_Float16)v.y,
               h2 = (_Float16)v.z, h3 = (_Float16)v.w;
      _Float16 l0 = (_Float16)((v.x - (float)h0) * 2048.0f);
      _Float16 l1 = (_Float16)((v.y - (float)h1) * 2048.0f);
      _Float16 l2 = (_Float16)((v.z - (float)h2) * 2048.0f);
      _Float16 l3 = (_Float16)((v.w - (float)h3) * 2048.0f);
      uint2 hp, lp;
      hp.x = (unsigned)f16bits(h0) | ((unsigned)f16bits(h1) << 16);
      hp.y = (unsigned)f16bits(h2) | ((unsigned)f16bits(h3) << 16);
      lp.x = (unsigned)f16bits(l0) | ((unsigned)f16bits(l1) << 16);
      lp.y = (unsigned)f16bits(l2) | ((unsigned)f16bits(l3) << 16);
      *reinterpret_cast<uint2*>(&Ah[row][jc * 4]) = hp;
      *reinterpret_cast<uint2*>(&Al[row][jc * 4]) = lp;
    }
    // ---- stage B from pre-converted W1t (row-contiguous 16B chunks) ----
#pragma unroll
    for (int i = 0; i < 4; ++i) {
      int q = tid + i * 256;               // 0..1023
      int sel = q >> 9;                    // 0 = hi, 1 = lo (uniform per i)
      int rem = q & 511;
      int row = rem >> 2, seg = rem & 3;
      const unsigned short* src =
          (sel ? W1tl : W1th) + (size_t)(n0 + row) * KDIM + k0 + seg * 8;
      uint4 d = *reinterpret_cast<const uint4*>(src);
      _Float16* dst = sel ? &Bl[row][seg * 8] : &Bh[row][seg * 8];
      *reinterpret_cast<uint4*>(dst) = d;
    }
    __syncthreads();
    // ---- fragments + MFMA ----
    f16x8 afh[4], afl[4], bfh[4], bfl[4];
#pragma unroll
    for (int m = 0; m < 4; ++m) {
      afh[m] = *reinterpret_cast<const f16x8*>(&Ah[wr * 64 + m * 16 + lrow][lk]);
      afl[m] = *reinterpret_cast<const f16x8*>(&Al[wr * 64 + m * 16 + lrow][lk]);
    }
#pragma unroll
    for (int n = 0; n < 4; ++n) {
      bfh[n] = *reinterpret_cast<const f16x8*>(&Bh[wc * 64 + n * 16 + lrow][lk]);
      bfl[n] = *reinterpret_cast<const f16x8*>(&Bl[wc * 64 + n * 16 + lrow][lk]);
    }
#pragma unroll
    for (int m = 0; m < 4; ++m)
#pragma unroll
      for (int n = 0; n < 4; ++n) {
        acc[m][n]  = __builtin_amdgcn_mfma_f32_16x16x32_f16(afh[m], bfh[n], acc[m][n], 0, 0, 0);
        acc2[m][n] = __builtin_amdgcn_mfma_f32_16x16x32_f16(afh[m], bfl[n], acc2[m][n], 0, 0, 0);
        acc2[m][n] = __builtin_amdgcn_mfma_f32_16x16x32_f16(afl[m], bfh[n], acc2[m][n], 0, 0, 0);
      }
  }

  // ---- epilogue: z = acc + acc2*2^-11 + bias; tanh; dot with Vw ----
  float part[4][4];
#pragma unroll
  for (int m = 0; m < 4; ++m)
#pragma unroll
    for (int r = 0; r < 4; ++r) part[m][r] = 0.f;
#pragma unroll
  for (int n = 0; n < 4; ++n) {
    int col = n0 + wc * 64 + n * 16 + lrow;
    float bias = W1b[col];
    float vw = Vw[col];
#pragma unroll
    for (int m = 0; m < 4; ++m)
#pragma unroll
      for (int r = 0; r < 4; ++r) {
        float z = acc[m][n][r] + acc2[m][n][r] * 4.8828125e-4f + bias;
        part[m][r] += tanhf(z) * vw;
      }
  }
  // reduce across the 16 column-lanes (lane&15)
#pragma unroll
  for (int off = 1; off < 16; off <<= 1)
#pragma unroll
    for (int m = 0; m < 4; ++m)
#pragma unroll
      for (int r = 0; r < 4; ++r)
        part[m][r] += __shfl_xor(part[m][r], off, 64);
  if (lrow == 0) {
#pragma unroll
    for (int m = 0; m < 4; ++m)
#pragma unroll
      for (int r = 0; r < 4; ++r)
        red[wc][wr * 64 + m * 16 + (lane >> 4) * 4 + r] = part[m][r];
  }
  __syncthreads();
  if (tid < BM)
    raw_part[(size_t)blockIdx.y * TM + m0 + tid] = red[0][tid] + red[1][tid];
}

// ---------------------------------------------------------------------------
// Kernel 3: per-cine (64 blocks): sum partials + Vb, stable-rank argsort,
// greedy temporal NMS (radius 13), sigmoid -> probs
// ---------------------------------------------------------------------------
__global__ __launch_bounds__(256) void nms_kernel(
    const float* __restrict__ raw_part,
    const float* __restrict__ Vb,
    float* __restrict__ probs)
{
  const int cine = blockIdx.x;
  const int t = threadIdx.x;
  __shared__ float s[256];
  __shared__ int order[256];
  const int idx = cine * 256 + t;
  float raw = raw_part[idx] + raw_part[TM + idx] + raw_part[2 * TM + idx] +
              raw_part[3 * TM + idx] + Vb[0];
  s[t] = raw;
  __syncthreads();
  // stable rank for descending sort (ties broken by smaller index first)
  float st = s[t];
  int rank = 0;
  for (int j = 0; j < 256; ++j) {
    float sj = s[j];
    rank += (sj > st) || (sj == st && j < t);
  }
  order[rank] = t;
  __syncthreads();
  if (t == 0) {
    unsigned long long mask[4] = {~0ull, ~0ull, ~0ull, ~0ull};
    for (int r = 0; r < 256; ++r) {
      int i = order[r];
      if ((mask[i >> 6] >> (i & 63)) & 1ull) {
        int lo = i - 13 < 0 ? 0 : i - 13;
        int hi = i + 13 > 255 ? 255 : i + 13;
        for (int b = lo; b <= hi; ++b)
          if (b != i) mask[b >> 6] &= ~(1ull << (b & 63));
      } else {
        s[i] = -3.402823466385289e+38f;  // float32 min (NEG_INF)
      }
    }
  }
  __syncthreads();
  probs[idx] = 1.0f / (1.0f + expf(-s[t]));
}

// ---------------------------------------------------------------------------
// Kernel 4: per-batch (8 blocks) nucleus top-p(0.7) on 2048 probs.
// Only nonzeros matter (zeros never reach cum<=p and contribute 0 anyway).
// Writes attn (out+12288) and masked_score (out+28672).
// ---------------------------------------------------------------------------
__global__ __launch_bounds__(256) void topp_kernel(
    const float* __restrict__ probs,
    float* __restrict__ out)
{
  const int b = blockIdx.x;
  const int tid = threadIdx.x;
  __shared__ float p[2048];
  __shared__ int cnz[2048];
  __shared__ float sv[2048];
  __shared__ int sidx[2048];
  __shared__ unsigned char msk[2048];
  __shared__ float red[256];
  __shared__ int nnz_s;

  if (tid == 0) nnz_s = 0;
  for (int i = tid; i < 2048; i += 256) {
    p[i] = probs[b * 2048 + i];
    msk[i] = 0;
  }
  __syncthreads();
  // compact nonzeros + total sum
  float lsum = 0.f;
  for (int i = tid; i < 2048; i += 256) {
    float v = p[i];
    lsum += v;
    if (v > 0.f) {
      int slot = atomicAdd(&nnz_s, 1);
      cnz[slot] = i;
    }
  }
  red[tid] = lsum;
  __syncthreads();
  for (int sred = 128; sred > 0; sred >>= 1) {
    if (tid < sred) red[tid] += red[tid + sred];
    __syncthreads();
  }
  const int nnz = nnz_s;
  const float total = red[0];
  // stable ranks among nonzeros (value desc, index asc)
  for (int c = tid; c < nnz; c += 256) {
    int i = cnz[c];
    float pi = p[i];
    int rank = 0;
    for (int cc = 0; cc < nnz; ++cc) {
      int j = cnz[cc];
      float pj = p[j];
      rank += (pj > pi) || (pj == pi && j < i);
    }
    sv[rank] = pi;
    sidx[rank] = i;
  }
  __syncthreads();
  if (tid == 0) {
    float denom = total + 1e-8f;
    float cum = 0.f;
    for (int r = 0; r < nnz; ++r) {
      cum += sv[r] / denom;             // norm then cumsum, like reference
      if ((cum <= 0.7f) || (r < 3)) msk[sidx[r]] = 1;
    }
  }
  __syncthreads();
  // masked scores + batch sum
  float ls = 0.f;
  for (int i = tid; i < 2048; i += 256) {
    float m = msk[i] ? p[i] : 0.f;
    sv[i] = m;                          // reuse sv as masked buffer
    ls += m;
  }
  red[tid] = ls;
  __syncthreads();
  for (int sred = 128; sred > 0; sred >>= 1) {
    if (tid < sred) red[tid] += red[tid + sred];
    __syncthreads();
  }
  const float ssum = red[0];
  const float denom = ssum + 1e-8f;
  const bool uni = (ssum <= 0.f);
  for (int i = tid; i < 2048; i += 256) {
    float m = sv[i];
    out[28672 + b * 2048 + i] = m;                       // masked_score
    out[12288 + b * 2048 + i] = uni ? (1.0f / 2048.0f) : (m / denom);  // attn
  }
}

// ---------------------------------------------------------------------------
// Kernel 5: sparse context partials: per (b,c) block, sum attn*values rows
// ---------------------------------------------------------------------------
__global__ __launch_bounds__(256) void ctx_part_kernel(
    const float* __restrict__ attn,     // out + 12288
    const float* __restrict__ values,
    float* __restrict__ ctxp)
{
  const int bc = blockIdx.x;            // b*8+c
  const int tid = threadIdx.x;
  __shared__ float a[256];
  a[tid] = attn[bc * 256 + tid];
  __syncthreads();
  float acc[6] = {0.f, 0.f, 0.f, 0.f, 0.f, 0.f};
  for (int t = 0; t < 256; ++t) {
    float at = a[t];
    if (at != 0.f) {
      const float* vrow = values + (size_t)(bc * 256 + t) * KDIM;
#pragma unroll
      for (int e = 0; e < 6; ++e) acc[e] += at * vrow[tid + e * 256];
    }
  }
#pragma unroll
  for (int e = 0; e < 6; ++e)
    ctxp[(size_t)bc * KDIM + tid + e * 256] = acc[e];
}

__global__ __launch_bounds__(256) void ctx_reduce_kernel(
    const float* __restrict__ ctxp,
    float* __restrict__ out)
{
  const int idx = blockIdx.x * 256 + threadIdx.x;  // 0..12287
  const int b = idx / KDIM, d = idx % KDIM;
  float sum = 0.f;
  for (int c = 0; c < 8; ++c) sum += ctxp[(size_t)(b * 8 + c) * KDIM + d];
  out[idx] = sum;
}

// ---------------------------------------------------------------------------
extern "C" void kernel_launch(void* const* d_in, const int* in_sizes, int n_in,
                              void* d_out, int out_size, void* d_ws, size_t ws_size,
                              hipStream_t stream) {
  const float* query  = (const float*)d_in[0];
  const float* values = (const float*)d_in[1];
  const float* W1w    = (const float*)d_in[2];
  const float* W1b    = (const float*)d_in[3];
  const float* Vw     = (const float*)d_in[4];
  const float* Vb     = (const float*)d_in[5];
  float* out = (float*)d_out;

  // ws layout (bytes): W1t_hi[786432 u16] | W1t_lo[786432 u16] |
  //                    raw_part[4*16384 f32] | probs[16384 f32] | ctxp[64*1536 f32]
  unsigned short* W1th = (unsigned short*)d_ws;
  unsigned short* W1tl = W1th + 786432;
  float* raw_part = (float*)((char*)d_ws + 3145728);
  float* probs    = raw_part + 4 * TM;
  float* ctxp     = probs + TM;

  convert_w1_kernel<<<dim3(24, 8), 256, 0, stream>>>(W1w, W1th, W1tl);
  gemm_score_kernel<<<dim3(TM / BM, NN / BN), 256, 0, stream>>>(
      query, W1th, W1tl, W1b, Vw, raw_part);
  nms_kernel<<<64, 256, 0, stream>>>(raw_part, Vb, probs);
  topp_kernel<<<8, 256, 0, stream>>>(probs, out);
  ctx_part_kernel<<<64, 256, 0, stream>>>(out + 12288, values, ctxp);
  ctx_reduce_kernel<<<48, 256, 0, stream>>>(ctxp, out);
}